// Round 11
// baseline (175.935 us; speedup 1.0000x reference)
//
#include <hip/hip_runtime.h>

#define N_NODES 50000
#define N_EDGES 800000
#define NE4 (N_EDGES / 4)
#define NMASKW 1568          // ceil(50000/32)=1563, padded
#define C1MAX 64             // unique layer-1 src cap (actual ~16)
#define CAP   16             // per-block dst==1 candidate cap
#define S2MAX 1024           // f2 slot cap (actual ~254)
#define DMAX  4096           // eD cap (actual ~256)
#define BK    96             // per-f2-slot bucket capacity (in-deg ~Poisson(16))
#define SB1   ((NE4 + 255) / 256)   // 782 scan blocks
#define GRIDB 768            // fused grid: 3 blocks/CU; launch_bounds(256,4) -> capacity 1024 >= 768
#define SUBW  64             // sub-counter stride in ints (256B apart)

#define AS(p, v)  __hip_atomic_store((p), (v), __ATOMIC_RELAXED, __HIP_MEMORY_SCOPE_AGENT)
#define ALD(p)    __hip_atomic_load((p), __ATOMIC_RELAXED, __HIP_MEMORY_SCOPE_AGENT)
#define AADD(p,v) __hip_atomic_fetch_add((p), (v), __ATOMIC_RELAXED, __HIP_MEMORY_SCOPE_AGENT)

__device__ __forceinline__ float lrelu(float v) { return v >= 0.f ? v : 0.01f * v; }
__device__ __forceinline__ bool mtest(const unsigned int* m, int i) {
    return (m[i >> 5] >> (i & 31)) & 1u;
}

// ---- K1 (atomic-free): per-block dst==1 candidates + zero the shared zone ----
__global__ __launch_bounds__(256) void scan1_k(const int4* __restrict__ dst4,
                                               const int* __restrict__ src,
                                               int* __restrict__ e1cnt, int* __restrict__ e1val,
                                               unsigned int* __restrict__ zbase, int zwords) {
    __shared__ int lcnt;
    __shared__ int lval[CAP];
    const int tid = threadIdx.x;
    const int t = blockIdx.x * 256 + tid;
    if (tid == 0) lcnt = 0;
    __syncthreads();
    if (t < zwords) zbase[t] = 0u;               // cooperative zone zero (~39 KB)
    if (t < NE4) {
        int4 d4 = dst4[t];
        int dv[4] = { d4.x, d4.y, d4.z, d4.w };
#pragma unroll
        for (int k = 0; k < 4; ++k) {
            if (dv[k] == 1) {
                int q = atomicAdd(&lcnt, 1);     // LDS atomic
                if (q < CAP) lval[q] = src[t * 4 + k];
            }
        }
    }
    __syncthreads();
    int c = lcnt < CAP ? lcnt : CAP;
    if (tid == 0) e1cnt[blockIdx.x] = c;
    if (tid < c) e1val[blockIdx.x * CAP + tid] = lval[tid];
}

// ---- K2: rebuild f1 set in LDS; f1[dst] -> eD=(src, rank1(dst)); f2 first-setter -> pos2 ----
__global__ __launch_bounds__(256) void scan2_k(const int4* __restrict__ dst4,
                                               const int* __restrict__ src,
                                               const int* __restrict__ e1cnt,
                                               const int* __restrict__ e1val,
                                               unsigned int* __restrict__ f2m,
                                               int* __restrict__ pos2, int* __restrict__ cnt2,
                                               int2* __restrict__ eD, int* __restrict__ cntD) {
    __shared__ unsigned int msk[NMASKW];
    __shared__ int candN[C1MAX];
    __shared__ int candC;
    const int tid = threadIdx.x;
    for (int k = tid; k < NMASKW; k += 256) msk[k] = 0u;
    if (tid == 0) candC = 0;
    __syncthreads();
    for (int b = tid; b < SB1; b += 256) {            // gather candidates (3KB, L2-hot)
        int c = e1cnt[b]; if (c > CAP) c = CAP;
        for (int i = 0; i < c; ++i) {
            int n = e1val[b * CAP + i];
            unsigned int bit = 1u << (n & 31);
            unsigned int old = atomicOr(&msk[n >> 5], bit);   // LDS atomic
            if (!(old & bit)) { int q = atomicAdd(&candC, 1); if (q < C1MAX) candN[q] = n; }
        }
    }
    __syncthreads();
    int c1 = candC; if (c1 > C1MAX) c1 = C1MAX;
    int t = blockIdx.x * 256 + tid;
    if (t >= NE4) return;
    int4 d4 = dst4[t];
    int dv[4] = { d4.x, d4.y, d4.z, d4.w };
#pragma unroll
    for (int k = 0; k < 4; ++k) {
        int dd = dv[k];
        if (mtest(msk, dd)) {
            int ss = src[t * 4 + k];
            unsigned int bit = 1u << (ss & 31);
            unsigned int old = atomicOr(&f2m[ss >> 5], bit);
            if (!(old & bit)) {
                int q2 = atomicAdd(cnt2, 1);
                if (q2 < S2MAX) AS(&pos2[ss], q2);
            }
            int r = 0;                                   // slot1 = ascending-id rank
            for (int u = 0; u < c1; ++u) r += (candN[u] < dd);
            int q = atomicAdd(cntD, 1);
            if (q < DMAX) {
                unsigned long long ev = (unsigned long long)(unsigned int)ss |
                                        ((unsigned long long)(unsigned int)r << 32);
                AS((unsigned long long*)&eD[q], ev);
            }
        }
    }
}

// ---- K3: f2[dst] -> bucket[pos2[dst]] += src; f3 first-setter -> zero agg0[src] ----
__global__ __launch_bounds__(256) void scan3_k(const int4* __restrict__ dst4,
                                               const int* __restrict__ src,
                                               const unsigned int* __restrict__ f2m,
                                               unsigned int* __restrict__ f3m,
                                               const int* __restrict__ pos2,
                                               float* __restrict__ agg0,
                                               int* __restrict__ bucket,
                                               int* __restrict__ slotCnt) {
    __shared__ unsigned int msk[NMASKW];
    const int tid = threadIdx.x;
    for (int k = tid; k < NMASKW; k += 256) msk[k] = f2m[k];
    __syncthreads();
    int t = blockIdx.x * 256 + tid;
    if (t >= NE4) return;
    int4 d4 = dst4[t];
    int dv[4] = { d4.x, d4.y, d4.z, d4.w };
#pragma unroll
    for (int k = 0; k < 4; ++k) {
        int dd = dv[k];
        if (mtest(msk, dd)) {
            int ss = src[t * 4 + k];
            unsigned int bit = 1u << (ss & 31);
            unsigned int old = atomicOr(&f3m[ss >> 5], bit);
            if (!(old & bit)) AS(&agg0[ss], 0.f);
            int sl = pos2[dd];
            if ((unsigned)sl < S2MAX) {
                int bi = atomicAdd(&slotCnt[sl], 1);
                if (bi < BK) AS(&bucket[sl * BK + bi], ss);
            }
        }
    }
}

// ---- K4 fused (768 blocks, 4 blocks/CU bound): [A] eDr remap + f3-filtered agg0
//      atomics -> grid barrier -> [B] slot GEMM + gacc scatter -> done -> [C] tail ----
struct P9 {
    const int4* dst4; const int4* src4; const float* x;
    const unsigned int* f3m; float* agg0;
    const int2* eD; const int* cntD; const int* pos2; int2* eDr;
    const int* bucket; const int* slotCnt; const int* cnt2;
    const int* e1cnt; const int* e1val;
    const float* W0; const float* b0; const float* W1; const float* b1;
    const float* W2; const float* b2; const float* W3; const float* b3;
    float* gacc; int* sub; int* top; int* rel; int* subB; int* topB; float* out;
};

__global__ __launch_bounds__(256, 4) void fused9_k(P9 p) {
    __shared__ unsigned int msk[NMASKW];
    __shared__ float xv[128];
    __shared__ float part[256];
    __shared__ float rowA[64];
    __shared__ float rowH[128];
    __shared__ float rowT[64];
    __shared__ float t3s[C1MAX];
    __shared__ int candN[C1MAX];
    __shared__ int candC;
    __shared__ int lflag;
    const int tid = threadIdx.x;
    const int gid = blockIdx.x * 256 + tid;
    const int g = tid >> 6, j = tid & 63;

    // ---- A: eDr remap (pos2 complete since scan2) + f3-filtered agg0 adds ----
    int cD = *p.cntD; if (cD > DMAX) cD = DMAX;
    if (gid < cD) {
        int2 e = p.eD[gid];                          // (src, rank1)
        int sl = p.pos2[e.x];
        unsigned long long ev =
            (unsigned long long)(unsigned int)((unsigned)sl < S2MAX ? sl : -1) |
            ((unsigned long long)(unsigned int)e.y << 32);
        AS((unsigned long long*)&p.eDr[gid], ev);
    }
    for (int k = tid; k < NMASKW; k += 256) msk[k] = p.f3m[k];
    __syncthreads();
    for (int t = gid; t < NE4; t += GRIDB * 256) {
        int4 d4 = p.dst4[t];
        bool m0 = mtest(msk, d4.x), m1 = mtest(msk, d4.y);
        bool m2 = mtest(msk, d4.z), m3 = mtest(msk, d4.w);
        if (m0 | m1 | m2 | m3) {
            int4 s4 = p.src4[t];
            if (m0) atomicAdd(&p.agg0[d4.x], p.x[s4.x]);
            if (m1) atomicAdd(&p.agg0[d4.y], p.x[s4.y]);
            if (m2) atomicAdd(&p.agg0[d4.z], p.x[s4.z]);
            if (m3) atomicAdd(&p.agg0[d4.w], p.x[s4.w]);
        }
    }
    // ---- grid barrier (co-resident: 768 blocks at 4/CU capacity) ----
    __syncthreads();
    if (tid == 0) {
        int s = blockIdx.x & 7;
        int old = AADD(&p.sub[s * SUBW], 1);
        if (old == (GRIDB / 8) - 1) {
            int o2 = AADD(p.top, 1);
            if (o2 == 7) AS(p.rel, 1);
        }
        while (ALD(p.rel) == 0) __builtin_amdgcn_s_sleep(8);
    }
    __syncthreads();

    // ---- B: slot loop (c2 ~254): bucket gather -> GEMM 64->128->64 -> scatter ----
    int c2 = *p.cnt2; if (c2 > S2MAX) c2 = S2MAX;
    const float w0 = p.W0[j], bb0 = p.b0[j];
    for (int b = blockIdx.x; b < c2; b += GRIDB) {
        int cnt = p.slotCnt[b]; if (cnt > BK) cnt = BK;
        if (tid < cnt) xv[tid] = p.agg0[p.bucket[b * BK + tid]];
        __syncthreads();
        float racc = 0.f;
        for (int m = g; m < cnt; m += 4) racc += lrelu(xv[m] * w0 + bb0);
        part[tid] = racc;
        __syncthreads();
        if (tid < 64)
            rowA[tid] = part[tid] + part[64 + tid] + part[128 + tid] + part[192 + tid];
        __syncthreads();
        if (tid < 128) {
            float h = p.b1[tid];
#pragma unroll
            for (int k = 0; k < 64; ++k) h += rowA[k] * p.W1[k * 128 + tid];
            rowH[tid] = lrelu(h);
        }
        __syncthreads();
        if (tid < 64) {
            float a2 = 0.f;
#pragma unroll
            for (int k = 0; k < 128; ++k) a2 += rowH[k] * p.W2[k * 64 + tid];
            rowT[tid] = a2;
        }
        __syncthreads();
        for (int base = 0; base < cD; base += 256) {     // producer-side scatter
            int i = base + tid;
            int2 e = make_int2(-1, -1);
            if (i < cD) e = p.eDr[i];
            bool m = (e.x == b);
            unsigned long long bal = __ballot(m);
            while (bal) {
                int bit = __builtin_ctzll(bal); bal &= bal - 1;
                int sl1 = __shfl(e.y, bit, 64);
                if ((unsigned)sl1 < C1MAX)
                    atomicAdd(&p.gacc[sl1 * 64 + j], rowT[j]);
            }
        }
        __syncthreads();
    }

    // ---- done-counter; last block runs the tail ----
    __syncthreads();
    if (tid == 0) {
        lflag = 0;
        int s = blockIdx.x & 7;
        int old = AADD(&p.subB[s * SUBW], 1);
        if (old == (GRIDB / 8) - 1) {
            int o2 = AADD(p.topB, 1);
            lflag = (o2 == 7);
        }
    }
    __syncthreads();
    if (!lflag) return;

    // ---- C: tail — rebuild candidates, t3 per rank, multiplicity sum ----
    for (int k = tid; k < NMASKW; k += 256) msk[k] = 0u;
    if (tid == 0) candC = 0;
    __syncthreads();
    for (int b = tid; b < SB1; b += 256) {
        int c = p.e1cnt[b]; if (c > CAP) c = CAP;
        for (int i = 0; i < c; ++i) {
            int n = p.e1val[b * CAP + i];
            unsigned int bit = 1u << (n & 31);
            unsigned int old = atomicOr(&msk[n >> 5], bit);
            if (!(old & bit)) { int q = atomicAdd(&candC, 1); if (q < C1MAX) candN[q] = n; }
        }
    }
    __syncthreads();
    int c1 = candC; if (c1 > C1MAX) c1 = C1MAX;
    int widx = tid >> 6;
    for (int q = widx; q < c1; q += 4) {
        int n = candN[q];
        int r = 0;
        for (int u = 0; u < c1; ++u) r += (candN[u] < n);
        float v = lrelu(p.gacc[r * 64 + j] + p.b2[j]) * p.W3[j];
        for (int off = 32; off > 0; off >>= 1) v += __shfl_down(v, off, 64);
        if (j == 0) t3s[r] = v;
    }
    __syncthreads();
    float ssum = 0.f;
    for (int b = tid; b < SB1; b += 256) {
        int c = p.e1cnt[b]; if (c > CAP) c = CAP;
        for (int i = 0; i < c; ++i) {
            int n = p.e1val[b * CAP + i];
            int r = 0;
            for (int u = 0; u < c1; ++u) r += (candN[u] < n);
            ssum += t3s[r];
        }
    }
    part[tid] = ssum;
    __syncthreads();
    for (int off = 128; off > 0; off >>= 1) {
        if (tid < off) part[tid] += part[tid + off];
        __syncthreads();
    }
    if (tid == 0) p.out[0] = lrelu(part[0] + p.b3[0]);
}

extern "C" void kernel_launch(void* const* d_in, const int* in_sizes, int n_in,
                              void* d_out, int out_size, void* d_ws, size_t ws_size,
                              hipStream_t stream) {
    const float* x   = (const float*)d_in[0];
    const int*   src = (const int*)d_in[1];
    const int*   dst = (const int*)d_in[2];
    const float* W0 = (const float*)d_in[3];  const float* b0 = (const float*)d_in[4];
    const float* W1 = (const float*)d_in[5];  const float* b1 = (const float*)d_in[6];
    const float* W2 = (const float*)d_in[7];  const float* b2 = (const float*)d_in[8];
    const float* W3 = (const float*)d_in[9];  const float* b3 = (const float*)d_in[10];
    float* out = (float*)d_out;
    const int4* dst4 = (const int4*)dst;
    const int4* src4 = (const int4*)src;

    char* base = (char*)d_ws;
    size_t off = 0;
    auto take = [&](size_t bytes) { char* q = base + off; off += (bytes + 255) & ~(size_t)255; return q; };
    // ---- zone: zeroed by scan1 (contiguous plain stores, flushed at kernel end) ----
    unsigned int* f2m = (unsigned int*)take(NMASKW * 4);
    unsigned int* f3m = (unsigned int*)take(NMASKW * 4);
    int* cnt2  = (int*)take(4);
    int* cntD  = (int*)take(4);
    int* top   = (int*)take(4);
    int* rel   = (int*)take(4);
    int* topB  = (int*)take(4);
    int* sub   = (int*)take((size_t)8 * SUBW * 4);
    int* subB  = (int*)take((size_t)8 * SUBW * 4);
    int* slotCnt = (int*)take((size_t)S2MAX * 4);
    float* gacc  = (float*)take((size_t)C1MAX * 64 * 4);
    int zwords = (int)(off / 4);
    // ---- uninitialized (written before read) ----
    float* agg0   = (float*)take((size_t)N_NODES * 4);
    int*   e1cnt  = (int*)take((size_t)SB1 * 4);
    int*   e1val  = (int*)take((size_t)SB1 * CAP * 4);
    int2*  eD     = (int2*)take((size_t)DMAX * 8);
    int2*  eDr    = (int2*)take((size_t)DMAX * 8);
    int*   bucket = (int*)take((size_t)S2MAX * BK * 4);
    int*   pos2   = (int*)take((size_t)N_NODES * 4);

    scan1_k<<<SB1, 256, 0, stream>>>(dst4, src, e1cnt, e1val, (unsigned int*)base, zwords);
    scan2_k<<<SB1, 256, 0, stream>>>(dst4, src, e1cnt, e1val, f2m, pos2, cnt2, eD, cntD);
    scan3_k<<<SB1, 256, 0, stream>>>(dst4, src, f2m, f3m, pos2, agg0, bucket, slotCnt);

    P9 hp;
    hp.dst4 = dst4; hp.src4 = src4; hp.x = x;
    hp.f3m = f3m; hp.agg0 = agg0;
    hp.eD = eD; hp.cntD = cntD; hp.pos2 = pos2; hp.eDr = eDr;
    hp.bucket = bucket; hp.slotCnt = slotCnt; hp.cnt2 = cnt2;
    hp.e1cnt = e1cnt; hp.e1val = e1val;
    hp.W0 = W0; hp.b0 = b0; hp.W1 = W1; hp.b1 = b1;
    hp.W2 = W2; hp.b2 = b2; hp.W3 = W3; hp.b3 = b3;
    hp.gacc = gacc; hp.sub = sub; hp.top = top; hp.rel = rel;
    hp.subB = subB; hp.topB = topB; hp.out = out;
    fused9_k<<<GRIDB, 256, 0, stream>>>(hp);
}

// Round 12
// 132.896 us; speedup vs baseline: 1.3239x; 1.3239x over previous
//
#include <hip/hip_runtime.h>

#define N_NODES 50000
#define N_EDGES 800000
#define NE4 (N_EDGES / 4)
#define NMASKW 1568          // ceil(50000/32)=1563, padded
#define C1MAX 64             // unique layer-1 src cap (actual ~16)
#define CAP   16             // per-block dst==1 candidate cap
#define S2MAX 1024           // f2 slot cap (actual ~254)
#define DMAX  4096           // eD cap (actual ~256)
#define BK    96             // per-f2-slot bucket capacity (in-deg ~Poisson(16))
#define SB1   ((NE4 + 255) / 256)   // 782 scan blocks
#define FGRID 256            // fused kernel grid (one scheduling wave)
#define SUBW  64             // sub-counter stride in ints (256B apart)

#define AS(p, v)  __hip_atomic_store((p), (v), __ATOMIC_RELAXED, __HIP_MEMORY_SCOPE_AGENT)
#define AADD(p,v) __hip_atomic_fetch_add((p), (v), __ATOMIC_RELAXED, __HIP_MEMORY_SCOPE_AGENT)

__device__ __forceinline__ float lrelu(float v) { return v >= 0.f ? v : 0.01f * v; }
__device__ __forceinline__ bool mtest(const unsigned int* m, int i) {
    return (m[i >> 5] >> (i & 31)) & 1u;
}

// ---- K1 (atomic-free): per-block dst==1 candidates + zero the shared zone ----
__global__ __launch_bounds__(256) void scan1_k(const int4* __restrict__ dst4,
                                               const int* __restrict__ src,
                                               int* __restrict__ e1cnt, int* __restrict__ e1val,
                                               unsigned int* __restrict__ zbase, int zwords) {
    __shared__ int lcnt;
    __shared__ int lval[CAP];
    const int tid = threadIdx.x;
    const int t = blockIdx.x * 256 + tid;
    if (tid == 0) lcnt = 0;
    __syncthreads();
    if (t < zwords) zbase[t] = 0u;               // cooperative zone zero (~39 KB)
    if (t < NE4) {
        int4 d4 = dst4[t];
        int dv[4] = { d4.x, d4.y, d4.z, d4.w };
#pragma unroll
        for (int k = 0; k < 4; ++k) {
            if (dv[k] == 1) {
                int q = atomicAdd(&lcnt, 1);     // LDS atomic
                if (q < CAP) lval[q] = src[t * 4 + k];
            }
        }
    }
    __syncthreads();
    int c = lcnt < CAP ? lcnt : CAP;
    if (tid == 0) e1cnt[blockIdx.x] = c;
    if (tid < c) e1val[blockIdx.x * CAP + tid] = lval[tid];
}

// ---- K2: rebuild f1 set in LDS; f1[dst] -> eD=(src, rank1(dst)); f2 first-setter -> pos2 ----
__global__ __launch_bounds__(256) void scan2_k(const int4* __restrict__ dst4,
                                               const int* __restrict__ src,
                                               const int* __restrict__ e1cnt,
                                               const int* __restrict__ e1val,
                                               unsigned int* __restrict__ f2m,
                                               int* __restrict__ pos2, int* __restrict__ cnt2,
                                               int2* __restrict__ eD, int* __restrict__ cntD) {
    __shared__ unsigned int msk[NMASKW];
    __shared__ int candN[C1MAX];
    __shared__ int candC;
    const int tid = threadIdx.x;
    for (int k = tid; k < NMASKW; k += 256) msk[k] = 0u;
    if (tid == 0) candC = 0;
    __syncthreads();
    for (int b = tid; b < SB1; b += 256) {            // gather candidates (3KB, L2-hot)
        int c = e1cnt[b]; if (c > CAP) c = CAP;
        for (int i = 0; i < c; ++i) {
            int n = e1val[b * CAP + i];
            unsigned int bit = 1u << (n & 31);
            unsigned int old = atomicOr(&msk[n >> 5], bit);   // LDS atomic
            if (!(old & bit)) { int q = atomicAdd(&candC, 1); if (q < C1MAX) candN[q] = n; }
        }
    }
    __syncthreads();
    int c1 = candC; if (c1 > C1MAX) c1 = C1MAX;
    int t = blockIdx.x * 256 + tid;
    if (t >= NE4) return;
    int4 d4 = dst4[t];
    int dv[4] = { d4.x, d4.y, d4.z, d4.w };
#pragma unroll
    for (int k = 0; k < 4; ++k) {
        int dd = dv[k];
        if (mtest(msk, dd)) {
            int ss = src[t * 4 + k];
            unsigned int bit = 1u << (ss & 31);
            unsigned int old = atomicOr(&f2m[ss >> 5], bit);
            if (!(old & bit)) {
                int q2 = atomicAdd(cnt2, 1);
                if (q2 < S2MAX) AS(&pos2[ss], q2);
            }
            int r = 0;                                   // slot1 = ascending-id rank
            for (int u = 0; u < c1; ++u) r += (candN[u] < dd);
            int q = atomicAdd(cntD, 1);
            if (q < DMAX) {
                unsigned long long ev = (unsigned long long)(unsigned int)ss |
                                        ((unsigned long long)(unsigned int)r << 32);
                AS((unsigned long long*)&eD[q], ev);
            }
        }
    }
}

// ---- K3: f2[dst] -> bucket[pos2[dst]] += src; f3 first-setter -> zero agg0[src] ----
__global__ __launch_bounds__(256) void scan3_k(const int4* __restrict__ dst4,
                                               const int* __restrict__ src,
                                               const unsigned int* __restrict__ f2m,
                                               unsigned int* __restrict__ f3m,
                                               const int* __restrict__ pos2,
                                               float* __restrict__ agg0,
                                               int* __restrict__ bucket,
                                               int* __restrict__ slotCnt) {
    __shared__ unsigned int msk[NMASKW];
    const int tid = threadIdx.x;
    for (int k = tid; k < NMASKW; k += 256) msk[k] = f2m[k];
    __syncthreads();
    int t = blockIdx.x * 256 + tid;
    if (t >= NE4) return;
    int4 d4 = dst4[t];
    int dv[4] = { d4.x, d4.y, d4.z, d4.w };
#pragma unroll
    for (int k = 0; k < 4; ++k) {
        int dd = dv[k];
        if (mtest(msk, dd)) {
            int ss = src[t * 4 + k];
            unsigned int bit = 1u << (ss & 31);
            unsigned int old = atomicOr(&f3m[ss >> 5], bit);
            if (!(old & bit)) AS(&agg0[ss], 0.f);
            int sl = pos2[dd];
            if ((unsigned)sl < S2MAX) {
                int bi = atomicAdd(&slotCnt[sl], 1);
                if (bi < BK) AS(&bucket[sl * BK + bi], ss);
            }
        }
    }
}

// ---- K4: f3[dst] -> agg0[dst] += x[src]; plus eDr remap (pos2 complete now) ----
__global__ __launch_bounds__(256) void scan4_k(const int4* __restrict__ dst4,
                                               const int4* __restrict__ src4,
                                               const float* __restrict__ x,
                                               const unsigned int* __restrict__ f3m,
                                               float* __restrict__ agg0,
                                               const int2* __restrict__ eD,
                                               const int* __restrict__ cntD,
                                               const int* __restrict__ pos2,
                                               int2* __restrict__ eDr) {
    __shared__ unsigned int msk[NMASKW];
    int g = blockIdx.x * 256 + threadIdx.x;
    {   // eDr[i] = (slot2(src), rank1) — parallel remap of the tiny eD list
        int cD = *cntD; if (cD > DMAX) cD = DMAX;
        if (g < cD) {
            int2 e = eD[g];
            int sl = pos2[e.x];
            unsigned long long ev =
                (unsigned long long)(unsigned int)((unsigned)sl < S2MAX ? sl : -1) |
                ((unsigned long long)(unsigned int)e.y << 32);
            AS((unsigned long long*)&eDr[g], ev);
        }
    }
    for (int k = threadIdx.x; k < NMASKW; k += 256) msk[k] = f3m[k];
    __syncthreads();
    if (g >= NE4) return;
    int4 d4 = dst4[g];
    bool m0 = mtest(msk, d4.x), m1 = mtest(msk, d4.y);
    bool m2 = mtest(msk, d4.z), m3 = mtest(msk, d4.w);
    if (m0 | m1 | m2 | m3) {
        int4 s4 = src4[g];
        if (m0) atomicAdd(&agg0[d4.x], x[s4.x]);
        if (m1) atomicAdd(&agg0[d4.y], x[s4.y]);
        if (m2) atomicAdd(&agg0[d4.z], x[s4.z]);
        if (m3) atomicAdd(&agg0[d4.w], x[s4.w]);
    }
}

// ---- K5: block per f2-slot: bucket gather + row GEMM -> rowT, producer-side
//          gacc scatter; hierarchical done; last block runs rank-based tail ----
struct P10 {
    const int* bucket; const int* slotCnt; const float* agg0;
    const float* W0; const float* b0; const float* W1; const float* b1;
    const float* W2; const float* b2; const float* W3; const float* b3;
    const int* cnt2; const int2* eDr; const int* cntD;
    const int* e1cnt; const int* e1val;
    float* gacc; int* sub; int* top; float* out;
};

__global__ __launch_bounds__(256) void fused10_k(P10 p) {
    __shared__ unsigned int msk[NMASKW];
    __shared__ float xv[128];
    __shared__ float part[256];
    __shared__ float rowA[64];
    __shared__ float rowH[128];
    __shared__ float rowT[64];
    __shared__ float t3s[C1MAX];
    __shared__ int candN[C1MAX];
    __shared__ int candC;
    __shared__ int lflag;
    const int tid = threadIdx.x;
    const int g = tid >> 6, j = tid & 63;
    int c2 = *p.cnt2; if (c2 > S2MAX) c2 = S2MAX;
    int cD = *p.cntD; if (cD > DMAX) cD = DMAX;
    const float w0 = p.W0[j], bb0 = p.b0[j];

    for (int b = blockIdx.x; b < c2; b += FGRID) {
        int cnt = p.slotCnt[b]; if (cnt > BK) cnt = BK;
        if (tid < cnt) xv[tid] = p.agg0[p.bucket[b * BK + tid]];   // parallel gather
        __syncthreads();
        float racc = 0.f;
        for (int m = g; m < cnt; m += 4) racc += lrelu(xv[m] * w0 + bb0);
        part[tid] = racc;
        __syncthreads();
        if (tid < 64)
            rowA[tid] = part[tid] + part[64 + tid] + part[128 + tid] + part[192 + tid];
        __syncthreads();
        if (tid < 128) {
            float h = p.b1[tid];
#pragma unroll
            for (int k = 0; k < 64; ++k) h += rowA[k] * p.W1[k * 128 + tid];
            rowH[tid] = lrelu(h);
        }
        __syncthreads();
        if (tid < 64) {
            float a2 = 0.f;
#pragma unroll
            for (int k = 0; k < 128; ++k) a2 += rowH[k] * p.W2[k * 64 + tid];
            rowT[tid] = a2;
        }
        __syncthreads();
        for (int base = 0; base < cD; base += 256) {     // producer-side scatter
            int i = base + tid;
            int2 e = make_int2(-1, -1);
            if (i < cD) e = p.eDr[i];
            bool m = (e.x == b);
            unsigned long long bal = __ballot(m);
            while (bal) {
                int bit = __builtin_ctzll(bal); bal &= bal - 1;
                int sl1 = __shfl(e.y, bit, 64);
                if ((unsigned)sl1 < C1MAX)
                    atomicAdd(&p.gacc[sl1 * 64 + j], rowT[j]);
            }
        }
        __syncthreads();      // protect LDS before next slot
    }

    // -- hierarchical done: __syncthreads drains the block's atomics;
    //    sub-counter (32 arrivals, separate lines) -> top (8 arrivals).
    __syncthreads();
    if (tid == 0) {
        lflag = 0;
        int s = blockIdx.x & 7;
        int old = AADD(&p.sub[s * SUBW], 1);
        if (old == (FGRID / 8) - 1) {
            int o2 = AADD(p.top, 1);
            lflag = (o2 == 7);
        }
    }
    __syncthreads();
    if (!lflag) return;

    // ---- tail: rebuild candidates, t3 per rank, multiplicity sum ----
    for (int k = tid; k < NMASKW; k += 256) msk[k] = 0u;
    if (tid == 0) candC = 0;
    __syncthreads();
    for (int b = tid; b < SB1; b += 256) {
        int c = p.e1cnt[b]; if (c > CAP) c = CAP;
        for (int i = 0; i < c; ++i) {
            int n = p.e1val[b * CAP + i];
            unsigned int bit = 1u << (n & 31);
            unsigned int old = atomicOr(&msk[n >> 5], bit);
            if (!(old & bit)) { int q = atomicAdd(&candC, 1); if (q < C1MAX) candN[q] = n; }
        }
    }
    __syncthreads();
    int c1 = candC; if (c1 > C1MAX) c1 = C1MAX;
    int widx = tid >> 6;
    for (int q = widx; q < c1; q += 4) {
        int n = candN[q];
        int r = 0;
        for (int u = 0; u < c1; ++u) r += (candN[u] < n);
        float v = lrelu(p.gacc[r * 64 + j] + p.b2[j]) * p.W3[j];
        for (int off = 32; off > 0; off >>= 1) v += __shfl_down(v, off, 64);
        if (j == 0) t3s[r] = v;
    }
    __syncthreads();
    float ssum = 0.f;
    for (int b = tid; b < SB1; b += 256) {
        int c = p.e1cnt[b]; if (c > CAP) c = CAP;
        for (int i = 0; i < c; ++i) {
            int n = p.e1val[b * CAP + i];
            int r = 0;
            for (int u = 0; u < c1; ++u) r += (candN[u] < n);
            ssum += t3s[r];
        }
    }
    part[tid] = ssum;
    __syncthreads();
    for (int off = 128; off > 0; off >>= 1) {
        if (tid < off) part[tid] += part[tid + off];
        __syncthreads();
    }
    if (tid == 0) p.out[0] = lrelu(part[0] + p.b3[0]);
}

extern "C" void kernel_launch(void* const* d_in, const int* in_sizes, int n_in,
                              void* d_out, int out_size, void* d_ws, size_t ws_size,
                              hipStream_t stream) {
    const float* x   = (const float*)d_in[0];
    const int*   src = (const int*)d_in[1];
    const int*   dst = (const int*)d_in[2];
    const float* W0 = (const float*)d_in[3];  const float* b0 = (const float*)d_in[4];
    const float* W1 = (const float*)d_in[5];  const float* b1 = (const float*)d_in[6];
    const float* W2 = (const float*)d_in[7];  const float* b2 = (const float*)d_in[8];
    const float* W3 = (const float*)d_in[9];  const float* b3 = (const float*)d_in[10];
    float* out = (float*)d_out;
    const int4* dst4 = (const int4*)dst;
    const int4* src4 = (const int4*)src;

    char* base = (char*)d_ws;
    size_t off = 0;
    auto take = [&](size_t bytes) { char* q = base + off; off += (bytes + 255) & ~(size_t)255; return q; };
    // ---- zone: zeroed by scan1 (contiguous plain stores, flushed at kernel end) ----
    unsigned int* f2m = (unsigned int*)take(NMASKW * 4);
    unsigned int* f3m = (unsigned int*)take(NMASKW * 4);
    int* cnt2  = (int*)take(4);
    int* cntD  = (int*)take(4);
    int* top   = (int*)take(4);
    int* sub   = (int*)take((size_t)8 * SUBW * 4);
    int* slotCnt = (int*)take((size_t)S2MAX * 4);
    float* gacc  = (float*)take((size_t)C1MAX * 64 * 4);
    int zwords = (int)(off / 4);
    // ---- uninitialized (written before read) ----
    float* agg0   = (float*)take((size_t)N_NODES * 4);
    int*   e1cnt  = (int*)take((size_t)SB1 * 4);
    int*   e1val  = (int*)take((size_t)SB1 * CAP * 4);
    int2*  eD     = (int2*)take((size_t)DMAX * 8);
    int2*  eDr    = (int2*)take((size_t)DMAX * 8);
    int*   bucket = (int*)take((size_t)S2MAX * BK * 4);
    int*   pos2   = (int*)take((size_t)N_NODES * 4);

    scan1_k<<<SB1, 256, 0, stream>>>(dst4, src, e1cnt, e1val, (unsigned int*)base, zwords);
    scan2_k<<<SB1, 256, 0, stream>>>(dst4, src, e1cnt, e1val, f2m, pos2, cnt2, eD, cntD);
    scan3_k<<<SB1, 256, 0, stream>>>(dst4, src, f2m, f3m, pos2, agg0, bucket, slotCnt);
    scan4_k<<<SB1, 256, 0, stream>>>(dst4, src4, x, f3m, agg0, eD, cntD, pos2, eDr);

    P10 hp;
    hp.bucket = bucket; hp.slotCnt = slotCnt; hp.agg0 = agg0;
    hp.W0 = W0; hp.b0 = b0; hp.W1 = W1; hp.b1 = b1;
    hp.W2 = W2; hp.b2 = b2; hp.W3 = W3; hp.b3 = b3;
    hp.cnt2 = cnt2; hp.eDr = eDr; hp.cntD = cntD;
    hp.e1cnt = e1cnt; hp.e1val = e1val;
    hp.gacc = gacc; hp.sub = sub; hp.top = top; hp.out = out;
    fused10_k<<<FGRID, 256, 0, stream>>>(hp);
}

// Round 13
// 128.283 us; speedup vs baseline: 1.3715x; 1.0360x over previous
//
#include <hip/hip_runtime.h>

#define N_NODES 50000
#define N_EDGES 800000
#define NE4 (N_EDGES / 4)
#define NMASKW 1568          // ceil(50000/32)=1563, padded
#define C1MAX 64             // unique layer-1 src cap (actual ~16)
#define CAP   16             // per-block dst==1 candidate cap
#define S2MAX 1024           // f2 slot cap (actual ~254)
#define DMAX  4096           // eD cap (actual ~256)
#define BK    96             // per-f2-slot bucket capacity (in-deg ~Poisson(16))
#define SB1   ((NE4 + 255) / 256)   // 782 scan blocks
#define FGRID 256            // slots kernel grid (one scheduling wave)

#define AS(p, v)  __hip_atomic_store((p), (v), __ATOMIC_RELAXED, __HIP_MEMORY_SCOPE_AGENT)

__device__ __forceinline__ float lrelu(float v) { return v >= 0.f ? v : 0.01f * v; }
__device__ __forceinline__ bool mtest(const unsigned int* m, int i) {
    return (m[i >> 5] >> (i & 31)) & 1u;
}

// ---- K1 (atomic-free): per-block dst==1 candidates + zero the shared zone ----
__global__ __launch_bounds__(256) void scan1_k(const int4* __restrict__ dst4,
                                               const int* __restrict__ src,
                                               int* __restrict__ e1cnt, int* __restrict__ e1val,
                                               unsigned int* __restrict__ zbase, int zwords) {
    __shared__ int lcnt;
    __shared__ int lval[CAP];
    const int tid = threadIdx.x;
    const int t = blockIdx.x * 256 + tid;
    if (tid == 0) lcnt = 0;
    __syncthreads();
    if (t < zwords) zbase[t] = 0u;               // cooperative zone zero (~40 KB)
    if (t < NE4) {
        int4 d4 = dst4[t];
        int dv[4] = { d4.x, d4.y, d4.z, d4.w };
#pragma unroll
        for (int k = 0; k < 4; ++k) {
            if (dv[k] == 1) {
                int q = atomicAdd(&lcnt, 1);     // LDS atomic
                if (q < CAP) lval[q] = src[t * 4 + k];
            }
        }
    }
    __syncthreads();
    int c = lcnt < CAP ? lcnt : CAP;
    if (tid == 0) e1cnt[blockIdx.x] = c;
    if (tid < c) e1val[blockIdx.x * CAP + tid] = lval[tid];
}

// ---- K2: rebuild f1 in LDS; publish cnt1g + per-rank multiplicity; f1[dst] ->
//          eD=(src, rank1(dst)); f2 first-setter -> pos2 slot ----
__global__ __launch_bounds__(256) void scan2_k(const int4* __restrict__ dst4,
                                               const int* __restrict__ src,
                                               const int* __restrict__ e1cnt,
                                               const int* __restrict__ e1val,
                                               unsigned int* __restrict__ f2m,
                                               int* __restrict__ pos2, int* __restrict__ cnt2,
                                               int2* __restrict__ eD, int* __restrict__ cntD,
                                               int* __restrict__ mult, int* __restrict__ cnt1g) {
    __shared__ unsigned int msk[NMASKW];
    __shared__ int candN[C1MAX];
    __shared__ int candC;
    const int tid = threadIdx.x;
    for (int k = tid; k < NMASKW; k += 256) msk[k] = 0u;
    if (tid == 0) candC = 0;
    __syncthreads();
    for (int b = tid; b < SB1; b += 256) {            // gather candidates (3KB, L2-hot)
        int c = e1cnt[b]; if (c > CAP) c = CAP;
        for (int i = 0; i < c; ++i) {
            int n = e1val[b * CAP + i];
            unsigned int bit = 1u << (n & 31);
            unsigned int old = atomicOr(&msk[n >> 5], bit);   // LDS atomic
            if (!(old & bit)) { int q = atomicAdd(&candC, 1); if (q < C1MAX) candN[q] = n; }
        }
    }
    __syncthreads();
    int c1 = candC; if (c1 > C1MAX) c1 = C1MAX;
    if (blockIdx.x == 0 && tid == 0) AS(cnt1g, c1);
    int t = blockIdx.x * 256 + tid;
    if (t >= NE4) return;
    int4 d4 = dst4[t];
    int dv[4] = { d4.x, d4.y, d4.z, d4.w };
#pragma unroll
    for (int k = 0; k < 4; ++k) {
        int dd = dv[k];
        if (dd == 1) {                                   // e1 edge: bump rank multiplicity
            int ss = src[t * 4 + k];
            int r = 0;
            for (int u = 0; u < c1; ++u) r += (candN[u] < ss);
            atomicAdd(&mult[r], 1);
        }
        if (mtest(msk, dd)) {
            int ss = src[t * 4 + k];
            unsigned int bit = 1u << (ss & 31);
            unsigned int old = atomicOr(&f2m[ss >> 5], bit);
            if (!(old & bit)) {
                int q2 = atomicAdd(cnt2, 1);
                if (q2 < S2MAX) AS(&pos2[ss], q2);
            }
            int r = 0;                                   // slot1 = ascending-id rank
            for (int u = 0; u < c1; ++u) r += (candN[u] < dd);
            int q = atomicAdd(cntD, 1);
            if (q < DMAX) {
                unsigned long long ev = (unsigned long long)(unsigned int)ss |
                                        ((unsigned long long)(unsigned int)r << 32);
                AS((unsigned long long*)&eD[q], ev);
            }
        }
    }
}

// ---- K3: f2[dst] -> bucket[pos2[dst]] += src; f3 first-setter -> zero agg0[src] ----
__global__ __launch_bounds__(256) void scan3_k(const int4* __restrict__ dst4,
                                               const int* __restrict__ src,
                                               const unsigned int* __restrict__ f2m,
                                               unsigned int* __restrict__ f3m,
                                               const int* __restrict__ pos2,
                                               float* __restrict__ agg0,
                                               int* __restrict__ bucket,
                                               int* __restrict__ slotCnt) {
    __shared__ unsigned int msk[NMASKW];
    const int tid = threadIdx.x;
    for (int k = tid; k < NMASKW; k += 256) msk[k] = f2m[k];
    __syncthreads();
    int t = blockIdx.x * 256 + tid;
    if (t >= NE4) return;
    int4 d4 = dst4[t];
    int dv[4] = { d4.x, d4.y, d4.z, d4.w };
#pragma unroll
    for (int k = 0; k < 4; ++k) {
        int dd = dv[k];
        if (mtest(msk, dd)) {
            int ss = src[t * 4 + k];
            unsigned int bit = 1u << (ss & 31);
            unsigned int old = atomicOr(&f3m[ss >> 5], bit);
            if (!(old & bit)) AS(&agg0[ss], 0.f);
            int sl = pos2[dd];
            if ((unsigned)sl < S2MAX) {
                int bi = atomicAdd(&slotCnt[sl], 1);
                if (bi < BK) AS(&bucket[sl * BK + bi], ss);
            }
        }
    }
}

// ---- K4: f3[dst] -> agg0[dst] += x[src]; plus eDr remap (pos2 complete now) ----
__global__ __launch_bounds__(256) void scan4_k(const int4* __restrict__ dst4,
                                               const int4* __restrict__ src4,
                                               const float* __restrict__ x,
                                               const unsigned int* __restrict__ f3m,
                                               float* __restrict__ agg0,
                                               const int2* __restrict__ eD,
                                               const int* __restrict__ cntD,
                                               const int* __restrict__ pos2,
                                               int2* __restrict__ eDr) {
    __shared__ unsigned int msk[NMASKW];
    int g = blockIdx.x * 256 + threadIdx.x;
    {   // eDr[i] = (slot2(src), rank1) — parallel remap of the tiny eD list
        int cD = *cntD; if (cD > DMAX) cD = DMAX;
        if (g < cD) {
            int2 e = eD[g];
            int sl = pos2[e.x];
            unsigned long long ev =
                (unsigned long long)(unsigned int)((unsigned)sl < S2MAX ? sl : -1) |
                ((unsigned long long)(unsigned int)e.y << 32);
            AS((unsigned long long*)&eDr[g], ev);
        }
    }
    for (int k = threadIdx.x; k < NMASKW; k += 256) msk[k] = f3m[k];
    __syncthreads();
    if (g >= NE4) return;
    int4 d4 = dst4[g];
    bool m0 = mtest(msk, d4.x), m1 = mtest(msk, d4.y);
    bool m2 = mtest(msk, d4.z), m3 = mtest(msk, d4.w);
    if (m0 | m1 | m2 | m3) {
        int4 s4 = src4[g];
        if (m0) atomicAdd(&agg0[d4.x], x[s4.x]);
        if (m1) atomicAdd(&agg0[d4.y], x[s4.y]);
        if (m2) atomicAdd(&agg0[d4.z], x[s4.z]);
        if (m3) atomicAdd(&agg0[d4.w], x[s4.w]);
    }
}

// ---- K5 (attribution target): block per f2-slot: bucket gather + row GEMM
//          64->128->64 -> rowT; producer-side gacc scatter. No tail, no done. ----
struct PS {
    const int* bucket; const int* slotCnt; const float* agg0;
    const float* W0; const float* b0; const float* W1; const float* b1; const float* W2;
    const int* cnt2; const int2* eDr; const int* cntD;
    float* gacc;
};

__global__ __launch_bounds__(256) void slots_k(PS p) {
    __shared__ float xv[128];
    __shared__ float part[256];
    __shared__ float rowA[64];
    __shared__ float rowH[128];
    __shared__ float rowT[64];
    const int tid = threadIdx.x;
    const int g = tid >> 6, j = tid & 63;
    int c2 = *p.cnt2; if (c2 > S2MAX) c2 = S2MAX;
    int cD = *p.cntD; if (cD > DMAX) cD = DMAX;
    const float w0 = p.W0[j], bb0 = p.b0[j];

    for (int b = blockIdx.x; b < c2; b += FGRID) {
        // issue the first scatter-list chunk early — independent of the GEMM chain
        int2 e0 = make_int2(-1, -1);
        if (tid < cD) e0 = p.eDr[tid];
        int cnt = p.slotCnt[b]; if (cnt > BK) cnt = BK;
        if (tid < cnt) xv[tid] = p.agg0[p.bucket[b * BK + tid]];   // parallel gather
        __syncthreads();
        float racc = 0.f;
        for (int m = g; m < cnt; m += 4) racc += lrelu(xv[m] * w0 + bb0);
        part[tid] = racc;
        __syncthreads();
        if (tid < 64)
            rowA[tid] = part[tid] + part[64 + tid] + part[128 + tid] + part[192 + tid];
        __syncthreads();
        if (tid < 128) {
            float h = p.b1[tid];
#pragma unroll
            for (int k = 0; k < 64; ++k) h += rowA[k] * p.W1[k * 128 + tid];
            rowH[tid] = lrelu(h);
        }
        __syncthreads();
        if (tid < 64) {
            float a2 = 0.f;
#pragma unroll
            for (int k = 0; k < 128; ++k) a2 += rowH[k] * p.W2[k * 64 + tid];
            rowT[tid] = a2;
        }
        __syncthreads();
        for (int base = 0; base < cD; base += 256) {     // producer-side scatter
            int i = base + tid;
            int2 e = (base == 0) ? e0 : make_int2(-1, -1);
            if (base != 0 && i < cD) e = p.eDr[i];
            bool m = (e.x == b);
            unsigned long long bal = __ballot(m);
            while (bal) {
                int bit = __builtin_ctzll(bal); bal &= bal - 1;
                int sl1 = __shfl(e.y, bit, 64);
                if ((unsigned)sl1 < C1MAX)
                    atomicAdd(&p.gacc[sl1 * 64 + j], rowT[j]);
            }
        }
        __syncthreads();      // protect LDS before next slot
    }
}

// ---- K6 (tiny): t3[r] = sum_j lrelu(gacc[r][j]+b2[j])*W3[j]; out = lrelu(sum mult[r]*t3[r] + b3) ----
__global__ __launch_bounds__(256) void tail_k(const float* __restrict__ gacc,
                                              const int* __restrict__ mult,
                                              const int* __restrict__ cnt1g,
                                              const float* __restrict__ b2,
                                              const float* __restrict__ W3,
                                              const float* __restrict__ b3,
                                              float* __restrict__ out) {
    __shared__ float t3s[C1MAX];
    const int tid = threadIdx.x, j = tid & 63, w = tid >> 6;
    int c1 = *cnt1g; if (c1 > C1MAX) c1 = C1MAX;
    for (int r = w; r < c1; r += 4) {
        float v = lrelu(gacc[r * 64 + j] + b2[j]) * W3[j];
        for (int off = 32; off > 0; off >>= 1) v += __shfl_down(v, off, 64);
        if (j == 0) t3s[r] = v;
    }
    __syncthreads();
    if (tid == 0) {
        float s = 0.f;
        for (int r = 0; r < c1; ++r) s += (float)mult[r] * t3s[r];
        out[0] = lrelu(s + b3[0]);
    }
}

extern "C" void kernel_launch(void* const* d_in, const int* in_sizes, int n_in,
                              void* d_out, int out_size, void* d_ws, size_t ws_size,
                              hipStream_t stream) {
    const float* x   = (const float*)d_in[0];
    const int*   src = (const int*)d_in[1];
    const int*   dst = (const int*)d_in[2];
    const float* W0 = (const float*)d_in[3];  const float* b0 = (const float*)d_in[4];
    const float* W1 = (const float*)d_in[5];  const float* b1 = (const float*)d_in[6];
    const float* W2 = (const float*)d_in[7];  const float* b2 = (const float*)d_in[8];
    const float* W3 = (const float*)d_in[9];  const float* b3 = (const float*)d_in[10];
    float* out = (float*)d_out;
    const int4* dst4 = (const int4*)dst;
    const int4* src4 = (const int4*)src;

    char* base = (char*)d_ws;
    size_t off = 0;
    auto take = [&](size_t bytes) { char* q = base + off; off += (bytes + 255) & ~(size_t)255; return q; };
    // ---- zone: zeroed by scan1 (contiguous plain stores, flushed at kernel end) ----
    unsigned int* f2m = (unsigned int*)take(NMASKW * 4);
    unsigned int* f3m = (unsigned int*)take(NMASKW * 4);
    int* cnt2  = (int*)take(4);
    int* cntD  = (int*)take(4);
    int* cnt1g = (int*)take(4);
    int* mult  = (int*)take((size_t)C1MAX * 4);
    int* slotCnt = (int*)take((size_t)S2MAX * 4);
    float* gacc  = (float*)take((size_t)C1MAX * 64 * 4);
    int zwords = (int)(off / 4);
    // ---- uninitialized (written before read) ----
    float* agg0   = (float*)take((size_t)N_NODES * 4);
    int*   e1cnt  = (int*)take((size_t)SB1 * 4);
    int*   e1val  = (int*)take((size_t)SB1 * CAP * 4);
    int2*  eD     = (int2*)take((size_t)DMAX * 8);
    int2*  eDr    = (int2*)take((size_t)DMAX * 8);
    int*   bucket = (int*)take((size_t)S2MAX * BK * 4);
    int*   pos2   = (int*)take((size_t)N_NODES * 4);

    scan1_k<<<SB1, 256, 0, stream>>>(dst4, src, e1cnt, e1val, (unsigned int*)base, zwords);
    scan2_k<<<SB1, 256, 0, stream>>>(dst4, src, e1cnt, e1val, f2m, pos2, cnt2, eD, cntD,
                                     mult, cnt1g);
    scan3_k<<<SB1, 256, 0, stream>>>(dst4, src, f2m, f3m, pos2, agg0, bucket, slotCnt);
    scan4_k<<<SB1, 256, 0, stream>>>(dst4, src4, x, f3m, agg0, eD, cntD, pos2, eDr);

    PS hp;
    hp.bucket = bucket; hp.slotCnt = slotCnt; hp.agg0 = agg0;
    hp.W0 = W0; hp.b0 = b0; hp.W1 = W1; hp.b1 = b1; hp.W2 = W2;
    hp.cnt2 = cnt2; hp.eDr = eDr; hp.cntD = cntD; hp.gacc = gacc;
    slots_k<<<FGRID, 256, 0, stream>>>(hp);

    tail_k<<<1, 256, 0, stream>>>(gacc, mult, cnt1g, b2, W3, b3, out);
}